// Round 3
// baseline (31.181 us; speedup 1.0000x reference)
//
#include <hip/hip_runtime.h>

#define LDIM 512
#define SITES (LDIM * LDIM)
#define H 8                     // rows per strip (per wave)
#define STRIPS (LDIM / H)       // 64 strips per batch
#define WPB 4                   // waves per block

__device__ __forceinline__ float spin_of(float x0, float x1) {
    // argmax tie-break: index 0 wins on equality -> spin -1
    return x1 > x0 ? 1.0f : -1.0f;
}

// One wave per strip: 64 lanes x 8 cols = full 512-wide row. Walks H rows
// with a 3-row rolling spin window and a distance-2 load pipeline; every row
// loaded exactly once (+2 halos, which are L2/L3-resident re-reads).
__global__ __launch_bounds__(256) void ising_strip(
        const float* __restrict__ x, float4* __restrict__ part) {
    const int b     = blockIdx.y;
    const int wave  = threadIdx.x >> 6;
    const int lane  = threadIdx.x & 63;
    const int strip = blockIdx.x * WPB + wave;
    const int r0    = strip * H;

    const float* xb = x + (size_t)b * (size_t)(SITES * 2);

    float4 xv[3][4];   // 3-deep ring: rows i-1 (dying), i, i+1 (landing)
    float  sp[3][8];   // rolling spins: rows i-1, i, i+1
    float A = 0.f, Hs = 0.f, T1 = 0.f, T2 = 0.f;

    #define LOADROW(row, dst)                                                  \
        {                                                                      \
            const float4* p_ =                                                 \
                (const float4*)(xb + (size_t)(row) * (LDIM * 2));              \
            _Pragma("unroll")                                                  \
            for (int q_ = 0; q_ < 4; ++q_) (dst)[q_] = p_[lane * 4 + q_];      \
        }
    #define SPINS(v, s)                                                        \
        {                                                                      \
            _Pragma("unroll")                                                  \
            for (int q_ = 0; q_ < 4; ++q_) {                                   \
                (s)[2 * q_]     = spin_of((v)[q_].x, (v)[q_].y);               \
                (s)[2 * q_ + 1] = spin_of((v)[q_].z, (v)[q_].w);               \
            }                                                                  \
        }

    // prologue: issue halo(-1), row0, row1 loads back-to-back, then spins
    {
        float4 tmp[4];
        LOADROW((r0 + LDIM - 1) & (LDIM - 1), tmp);
        LOADROW(r0, xv[0]);
        LOADROW((r0 + 1) & (LDIM - 1), xv[1]);
        SPINS(tmp, sp[0]);       // row r0-1
        SPINS(xv[0], sp[1]);     // row r0
    }

    const int laneL = (lane + 63) & 63;
    const int laneR = (lane + 1) & 63;

    #pragma unroll
    for (int i = 0; i < H; ++i) {
        // issue load of row i+2 (lands one iteration from now)
        if (i <= H - 2) LOADROW((r0 + i + 2) & (LDIM - 1), xv[(i + 2) % 3]);

        float* sP = sp[i % 3];          // row i-1
        float* sC = sp[(i + 1) % 3];    // row i
        float* sN = sp[(i + 2) % 3];    // row i+1
        SPINS(xv[(i + 1) % 3], sN);     // consumes load issued at iter i-1

        const float sl = __shfl(sC[7], laneL);  // torus col wrap (wave = row)
        const float sr = __shfl(sC[0], laneR);

        #pragma unroll
        for (int k = 0; k < 8; ++k) {
            const float lft = (k == 0) ? sl : sC[k - 1];
            const float rgt = (k == 7) ? sr : sC[k + 1];
            const float h   = lft + rgt + sP[k] + sN[k];
            const float4 v  = xv[i % 3][k >> 1];
            const float x0  = (k & 1) ? v.z : v.x;
            const float x1  = (k & 1) ? v.w : v.y;
            const float a   = x0 + x1;
            const float d   = x0 - x1;
            const float sh  = sC[k] * h;
            A  += a;
            Hs += sh;
            T1 += a * sh;
            T2 += d * h;
        }
    }

    #pragma unroll
    for (int off = 32; off; off >>= 1) {
        A  += __shfl_down(A,  off);
        Hs += __shfl_down(Hs, off);
        T1 += __shfl_down(T1, off);
        T2 += __shfl_down(T2, off);
    }
    if (lane == 0) part[b * STRIPS + strip] = make_float4(A, Hs, T1, T2);

    #undef LOADROW
    #undef SPINS
}

// One block (single wave) per batch: reduce STRIPS partials, apply closed form.
__global__ __launch_bounds__(64) void ising_final(
        const float4* __restrict__ part, float* __restrict__ out) {
    const int b = blockIdx.x;
    const int t = threadIdx.x;
    float4 v = part[b * STRIPS + t];
    float A = v.x, Hs = v.y, T1 = v.z, T2 = v.w;
    #pragma unroll
    for (int off = 32; off; off >>= 1) {
        A  += __shfl_down(A,  off);
        Hs += __shfl_down(Hs, off);
        T1 += __shfl_down(T1, off);
        T2 += __shfl_down(T2, off);
    }
    if (t == 0) {
        const float total = -0.5f * Hs * A + T1 + T2;
        out[b] = total * (1.0f / (float)SITES);
    }
}

extern "C" void kernel_launch(void* const* d_in, const int* in_sizes, int n_in,
                              void* d_out, int out_size, void* d_ws, size_t ws_size,
                              hipStream_t stream) {
    const float* x = (const float*)d_in[0];
    float* out = (float*)d_out;
    float4* part = (float4*)d_ws;   // B * STRIPS float4 partials (64 KiB for B=64)

    const int B = in_sizes[0] / (SITES * 2);

    dim3 grid(STRIPS / WPB, B);     // 16 x 64 = 1024 blocks, 4 waves each
    ising_strip<<<grid, WPB * 64, 0, stream>>>(x, part);
    ising_final<<<B, STRIPS, 0, stream>>>(part, out);
}